// Round 11
// baseline (119.371 us; speedup 1.0000x reference)
//
#include <hip/hip_runtime.h>
#include <hip/hip_bf16.h>
#include <math.h>

#define TOK 16384
#define HDIM 2048
#define NE 64
#define NB 4
#define KTOP 8
#define KC 64
#define NC (HDIM / KC)   // 32 chunks
#define BT 32            // tokens per block
#define WCH 16384        // bytes per f32 W chunk in wpk

typedef __attribute__((ext_vector_type(8))) __bf16 bf16x8;
typedef __attribute__((ext_vector_type(4))) float f32x4;
typedef unsigned int uint;

__device__ __forceinline__ uint asu(float f) { union { float f; uint u; } c; c.f = f; return c.u; }
__device__ __forceinline__ float asf(uint u) { union { uint u; float f; } c; c.u = u; return c.f; }

// Exact 3-way bf16 split: h+m+l == x bitwise (8 mantissa bits per plane).
__device__ __forceinline__ void split3(float v, uint& h, uint& m, uint& l) {
  uint u = asu(v);
  h = u & 0xffff0000u;
  float d = v - asf(h);
  m = asu(d) & 0xffff0000u;
  float d2 = d - asf(m);
  l = asu(d2);
}

// 8 floats (one fragment k-slot) -> 3 bf16x8 planes, in-register.
__device__ __forceinline__ void split8(float4 a, float4 b,
                                       bf16x8& h8, bf16x8& m8, bf16x8& l8) {
  union { uint4 u; bf16x8 v; } H, M, L;
  uint h0, m0, l0, h1, m1, l1;
  split3(a.x, h0, m0, l0); split3(a.y, h1, m1, l1);
  H.u.x = (h0 >> 16) | (h1 & 0xffff0000u);
  M.u.x = (m0 >> 16) | (m1 & 0xffff0000u);
  L.u.x = (l0 >> 16) | (l1 & 0xffff0000u);
  split3(a.z, h0, m0, l0); split3(a.w, h1, m1, l1);
  H.u.y = (h0 >> 16) | (h1 & 0xffff0000u);
  M.u.y = (m0 >> 16) | (m1 & 0xffff0000u);
  L.u.y = (l0 >> 16) | (l1 & 0xffff0000u);
  split3(b.x, h0, m0, l0); split3(b.y, h1, m1, l1);
  H.u.z = (h0 >> 16) | (h1 & 0xffff0000u);
  M.u.z = (m0 >> 16) | (m1 & 0xffff0000u);
  L.u.z = (l0 >> 16) | (l1 & 0xffff0000u);
  split3(b.z, h0, m0, l0); split3(b.w, h1, m1, l1);
  H.u.w = (h0 >> 16) | (h1 & 0xffff0000u);
  M.u.w = (m0 >> 16) | (m1 & 0xffff0000u);
  L.u.w = (l0 >> 16) | (l1 & 0xffff0000u);
  h8 = H.v; m8 = M.v; l8 = L.v;
}

__device__ __forceinline__ void gl_lds16(const void* g, void* l) {
  __builtin_amdgcn_global_load_lds(
      (const __attribute__((address_space(1))) void*)g,
      (__attribute__((address_space(3))) void*)l, 16, 0, 0);
}

// ---------------------------------------------------------------------------
// wpack: reorder W (f32, no split) into fragment-linear chunks; zero stats.
// Slot t (16 B): c = t>>10, g = (t>>6)&15, lane = t&63;
//   g = ks*8 + half*4 + f2*2 + h16
//   e = half*32 + f2*16 + (lane&15); k = c*64 + ks*32 + (lane>>4)*8 + h16*4
// ---------------------------------------------------------------------------
__global__ __launch_bounds__(256) void wpack(const float* __restrict__ w,
                                             char* __restrict__ wpk,
                                             float* __restrict__ stats) {
  if (blockIdx.x == 0 && threadIdx.x < 132) {   // zero ce+ssum+cnt
    *(float4*)(stats + threadIdx.x * 4) = make_float4(0.f, 0.f, 0.f, 0.f);
  }
  int t = blockIdx.x * 256 + threadIdx.x;       // 0..32767
  int c = t >> 10;
  int g = (t >> 6) & 15;
  int lane = t & 63;
  int ks = g >> 3, half = (g >> 2) & 1, f2 = (g >> 1) & 1, h16 = g & 1;
  int e = half * 32 + f2 * 16 + (lane & 15);
  int k = c * 64 + ks * 32 + ((lane >> 4) << 3) + h16 * 4;
  *(uint4*)(wpk + (size_t)t * 16) = *(const uint4*)(w + (size_t)e * HDIM + k);
}

// ---------------------------------------------------------------------------
// Fused gate. 512 blocks x 256 thr (4 waves), 2 blocks/CU.
// Wave = 16 tokens x 32 experts (2 C-frags). r9 structure (best: all-LDS
// staging, vmcnt(0)+barrier per chunk) with ONE change: W staged as raw f32
// (16 KB/chunk vs 24 KB bf16x3) and split3'd IN-REGISTER after ds_read --
// staged bytes/CU/chunk drop 64->48 KB (the measured delivery-bound term),
// paid for with VALU (the idle pipe, 24% busy).
// LDS: W dbuf 2x16 KB @0, X dbuf 2x8 KB @32768. 48 KB -> 2 blocks/CU.
// ---------------------------------------------------------------------------
__global__ __launch_bounds__(256, 2) void gate_fused(const float* __restrict__ x,
                                                     const char* __restrict__ wpk,
                                                     float* __restrict__ out,
                                                     float* __restrict__ ce,
                                                     float* __restrict__ ssum,
                                                     int* __restrict__ cnt) {
  __shared__ __align__(16) char lds[49152];
  __shared__ float hist[NE];
  __shared__ int lastflag;

  const int tid = threadIdx.x;
  const int bid = blockIdx.x;
  const int t0 = bid * BT;
  const int b = bid >> 7;                     // 128 blocks per batch row
  const int lane = tid & 63;
  const int wid = tid >> 6;                   // 0..3
  const int half = wid & 1;                   // expert half
  const int tg = (wid >> 1);                  // token group: 0 or 1

  if (tid < NE) hist[tid] = 0.f;

  // X staging (r9 verbatim): 2 slots/thread, per-lane swizzled source,
  // wave-uniform dest. Slot s = r*256+tid: row = t0+r*16+(lane&15),
  // k-off = (wid>>1)*32 + (lane>>4)*8 + (wid&1)*4.
  const char* xsg[2];
  int xdo_[2];
#pragma unroll
  for (int r = 0; r < 2; ++r) {
    int s = r * 256 + tid;
    int stg = s >> 8, sks = (s >> 7) & 1, sq = (s >> 6) & 1, ln = s & 63;
    xsg[r] = (const char*)(x + (size_t)(t0 + stg * 16 + (ln & 15)) * HDIM
                           + sks * 32 + ((ln >> 4) << 3) + sq * 4);
    xdo_[r] = (r * 256 + wid * 64) * 16;      // wave-uniform dest offset
  }
  const char* wsrc = wpk + (size_t)lane * 16;

  f32x4 acc[2] = {{0.f, 0.f, 0.f, 0.f}, {0.f, 0.f, 0.f, 0.f}};

#define STAGE(cc, sel)                                                        \
  {                                                                           \
    const char* wp_ = wsrc + (size_t)(cc) * WCH;                              \
    char* wd_ = lds + (sel) * WCH;                                            \
    _Pragma("unroll")                                                         \
    for (int r = 0; r < 4; ++r)                                               \
      gl_lds16(wp_ + (r * 4 + wid) * 1024, wd_ + (r * 4 + wid) * 1024);       \
    char* xdst = lds + 32768 + (sel) * 8192;                                  \
    _Pragma("unroll")                                                         \
    for (int r = 0; r < 2; ++r)                                               \
      gl_lds16(xsg[r] + (size_t)(cc) * 256, xdst + xdo_[r]);                  \
  }

  // ---- prologue: stage chunk 0, drain, barrier
  STAGE(0, 0);
  asm volatile("s_waitcnt vmcnt(0)" ::: "memory");
  __builtin_amdgcn_s_barrier();
  asm volatile("" ::: "memory");

#pragma unroll 1
  for (int c = 0; c < NC; ++c) {
    const int sel = c & 1;
    if (c + 1 < NC) STAGE(c + 1, sel ^ 1);    // 1: stage next chunk (async)

    char* wb = lds + sel * WCH;
    char* xb = lds + 32768 + sel * 8192 + tg * 4096;
#pragma unroll
    for (int ks = 0; ks < 2; ++ks) {          // 2: read LDS, split, MFMA
      float4 X0 = *(const float4*)(xb + ks * 2048 + lane * 16);
      float4 X1 = *(const float4*)(xb + ks * 2048 + 1024 + lane * 16);
      bf16x8 ah, am, al;
      split8(X0, X1, ah, am, al);
#pragma unroll
      for (int f2 = 0; f2 < 2; ++f2) {
        const int g = ks * 8 + half * 4 + f2 * 2;
        float4 W0 = *(const float4*)(wb + g * 1024 + lane * 16);
        float4 W1 = *(const float4*)(wb + (g + 1) * 1024 + lane * 16);
        bf16x8 bh, bm, bl;
        split8(W0, W1, bh, bm, bl);
        acc[f2] = __builtin_amdgcn_mfma_f32_16x16x32_bf16(ah, bh, acc[f2], 0, 0, 0);
        acc[f2] = __builtin_amdgcn_mfma_f32_16x16x32_bf16(ah, bm, acc[f2], 0, 0, 0);
        acc[f2] = __builtin_amdgcn_mfma_f32_16x16x32_bf16(am, bh, acc[f2], 0, 0, 0);
        acc[f2] = __builtin_amdgcn_mfma_f32_16x16x32_bf16(ah, bl, acc[f2], 0, 0, 0);
        acc[f2] = __builtin_amdgcn_mfma_f32_16x16x32_bf16(al, bh, acc[f2], 0, 0, 0);
        acc[f2] = __builtin_amdgcn_mfma_f32_16x16x32_bf16(am, bm, acc[f2], 0, 0, 0);
      }
    }
    // 3: drain the staging issued at top of THIS chunk; barrier
    asm volatile("s_waitcnt vmcnt(0)" ::: "memory");
    __builtin_amdgcn_s_barrier();
    asm volatile("" ::: "memory");
  }
#undef STAGE

  // C frags -> sc[expert][token]. C layout: col(=expert)=lane&15,
  // row(=token)=(lane>>4)*4+reg  [m89-verified]
  float (*sc)[BT + 1] = (float(*)[BT + 1])lds;
#pragma unroll
  for (int f2 = 0; f2 < 2; ++f2) {
    int e = half * 32 + f2 * 16 + (lane & 15);
    int tk = tg * 16 + ((lane >> 4) << 2);
    sc[e][tk + 0] = acc[f2][0];
    sc[e][tk + 1] = acc[f2][1];
    sc[e][tk + 2] = acc[f2][2];
    sc[e][tk + 3] = acc[f2][3];
  }
  __syncthreads();

  // softmax + top-8: 8 lanes per token (t = 0..31), 8 experts per lane
  const int t = tid >> 3;
  const int j = tid & 7;
  float p[8];
#pragma unroll
  for (int i = 0; i < 8; ++i) p[i] = sc[j * 8 + i][t];

  float m = p[0];
#pragma unroll
  for (int i = 1; i < 8; ++i) m = fmaxf(m, p[i]);
  m = fmaxf(m, __shfl_xor(m, 1, 8));
  m = fmaxf(m, __shfl_xor(m, 2, 8));
  m = fmaxf(m, __shfl_xor(m, 4, 8));
  float s = 0.f;
#pragma unroll
  for (int i = 0; i < 8; ++i) { p[i] = __expf(p[i] - m); s += p[i]; }
  s += __shfl_xor(s, 1, 8);
  s += __shfl_xor(s, 2, 8);
  s += __shfl_xor(s, 4, 8);
  float inv = 1.f / s;
#pragma unroll
  for (int i = 0; i < 8; ++i) { p[i] *= inv; sc[j * 8 + i][t] = p[i]; }

  // top-8: strict-> scan (lowest idx on tie), 8-lane (val,idx) reduce
  unsigned used = 0;
  float wsum = 0.f;
  float wv[KTOP];
  int wi_[KTOP];
#pragma unroll
  for (int sel = 0; sel < KTOP; ++sel) {
    float bv = -1.f;
    int bi = 0;
#pragma unroll
    for (int i = 0; i < 8; ++i) {
      bool ok = !((used >> i) & 1u);
      if (ok && p[i] > bv) { bv = p[i]; bi = i; }
    }
    int ge = j * 8 + bi;
#pragma unroll
    for (int mk = 1; mk < 8; mk <<= 1) {
      float ov = __shfl_xor(bv, mk, 8);
      int og = __shfl_xor(ge, mk, 8);
      if (ov > bv || (ov == bv && og < ge)) { bv = ov; ge = og; }
    }
    if ((ge >> 3) == j) used |= 1u << (ge & 7);
    wv[sel] = bv;
    wi_[sel] = ge;
    wsum += bv;
  }
  if (j == 0) {
    float winv = 1.f / (wsum + 1e-20f);
#pragma unroll
    for (int sel = 0; sel < KTOP; ++sel) {
      out[(size_t)(t0 + t) * KTOP + sel] = (float)wi_[sel];
      out[(size_t)TOK * KTOP + (size_t)(t0 + t) * KTOP + sel] = wv[sel] * winv;
      atomicAdd(&hist[wi_[sel]], 1.f);
    }
  }
  __syncthreads();

  if (tid < NE) {
    float ssl = 0.f;
#pragma unroll
    for (int tt = 0; tt < BT; ++tt) ssl += sc[tid][tt];
    atomicAdd(&ssum[b * NE + tid], ssl);
    atomicAdd(&ce[b * NE + tid], hist[tid]);
  }

  // ---- merged finalize: last block computes loads + aux_loss.
  // ce/ssum read via atomicAdd(p, 0) -> coherent at the atomic point
  // (avoids any stale per-XCD L2 copy).
  __threadfence();
  __syncthreads();
  if (tid == 0) lastflag = (atomicAdd(cnt, 1) == (int)gridDim.x - 1);
  __syncthreads();
  if (lastflag && tid < 64) {
    const int e = tid;
    float loads = 0.f, aux = 0.f;
#pragma unroll
    for (int b2 = 0; b2 < NB; ++b2) {
      float cv = atomicAdd(&ce[b2 * 64 + e], 0.f);
      float sv = atomicAdd(&ssum[b2 * 64 + e], 0.f);
      loads += cv;
      aux += (cv / 512.0f) * (sv / 4096.0f);  // (S*K/E)=512, S=4096
    }
    out[(size_t)2 * TOK * KTOP + 1 + e] = loads;
#pragma unroll
    for (int off = 32; off > 0; off >>= 1) aux += __shfl_down(aux, off);
    if (e == 0) out[(size_t)2 * TOK * KTOP] = aux * (0.1f / 4.0f);  // ALPHA/B
  }
}

extern "C" void kernel_launch(void* const* d_in, const int* in_sizes, int n_in,
                              void* d_out, int out_size, void* d_ws, size_t ws_size,
                              hipStream_t stream) {
  const float* x = (const float*)d_in[0];
  const float* w = (const float*)d_in[1];
  float* out = (float*)d_out;

  char* wpk = (char*)d_ws;                          // 32 chunks x 16 KB = 512 KB
  float* ce = (float*)(wpk + (size_t)NC * WCH);     // [NB][NE]
  float* ssum = ce + NB * NE;                       // [NB][NE]
  int* cnt = (int*)(ssum + NB * NE);                // completion counter

  wpack<<<dim3(128), dim3(256), 0, stream>>>(w, wpk, ce);
  gate_fused<<<dim3(TOK / BT), dim3(256), 0, stream>>>(x, wpk, out, ce, ssum, cnt);
}

// Round 12
// 94.655 us; speedup vs baseline: 1.2611x; 1.2611x over previous
//
#include <hip/hip_runtime.h>
#include <hip/hip_bf16.h>
#include <math.h>

#define TOK 16384
#define HDIM 2048
#define NE 64
#define NB 4
#define KTOP 8
#define KC 64
#define NC (HDIM / KC)   // 32 chunks
#define BT 32            // tokens per block

typedef __attribute__((ext_vector_type(8))) __bf16 bf16x8;
typedef __attribute__((ext_vector_type(16))) float f32x16;
typedef unsigned int uint;

__device__ __forceinline__ uint asu(float f) { union { float f; uint u; } c; c.f = f; return c.u; }
__device__ __forceinline__ float asf(uint u) { union { uint u; float f; } c; c.u = u; return c.f; }

// Exact 3-way bf16 split: h+m+l == x bitwise (8 mantissa bits per plane).
__device__ __forceinline__ void split3(float v, uint& h, uint& m, uint& l) {
  uint u = asu(v);
  h = u & 0xffff0000u;
  float d = v - asf(h);
  m = asu(d) & 0xffff0000u;
  float d2 = d - asf(m);
  l = asu(d2);
}

// 8 floats (one fragment k-slot) -> 3 bf16x8 planes, in-register.
__device__ __forceinline__ void split8(float4 a, float4 b,
                                       bf16x8& h8, bf16x8& m8, bf16x8& l8) {
  union { uint4 u; bf16x8 v; } H, M, L;
  uint h0, m0, l0, h1, m1, l1;
  split3(a.x, h0, m0, l0); split3(a.y, h1, m1, l1);
  H.u.x = (h0 >> 16) | (h1 & 0xffff0000u);
  M.u.x = (m0 >> 16) | (m1 & 0xffff0000u);
  L.u.x = (l0 >> 16) | (l1 & 0xffff0000u);
  split3(a.z, h0, m0, l0); split3(a.w, h1, m1, l1);
  H.u.y = (h0 >> 16) | (h1 & 0xffff0000u);
  M.u.y = (m0 >> 16) | (m1 & 0xffff0000u);
  L.u.y = (l0 >> 16) | (l1 & 0xffff0000u);
  split3(b.x, h0, m0, l0); split3(b.y, h1, m1, l1);
  H.u.z = (h0 >> 16) | (h1 & 0xffff0000u);
  M.u.z = (m0 >> 16) | (m1 & 0xffff0000u);
  L.u.z = (l0 >> 16) | (l1 & 0xffff0000u);
  split3(b.z, h0, m0, l0); split3(b.w, h1, m1, l1);
  H.u.w = (h0 >> 16) | (h1 & 0xffff0000u);
  M.u.w = (m0 >> 16) | (m1 & 0xffff0000u);
  L.u.w = (l0 >> 16) | (l1 & 0xffff0000u);
  h8 = H.v; m8 = M.v; l8 = L.v;
}

__device__ __forceinline__ void gl_lds16(const void* g, void* l) {
  __builtin_amdgcn_global_load_lds(
      (const __attribute__((address_space(1))) void*)g,
      (__attribute__((address_space(3))) void*)l, 16, 0, 0);
}

// ---------------------------------------------------------------------------
// wpack32: pack W into 32x32x16 B-fragment order, 3 exact bf16 planes; zero
// stats. Thread t: c = t>>9, kstep = (t>>7)&3, ehalf = (t>>6)&1, lane = t&63.
//   e = ehalf*32 + (lane&31); k = c*64 + kstep*16 + (lane>>5)*8
//   byte = c*24576 + kstep*6144 + ehalf*3072 + plane*1024 + lane*16
// (B-frag mapping: col = lane&31, k-slot = (lane>>5)*8 — standard CDNA,
//  consistent with session-verified 16x16 layouts and m74/m101 C layout.)
// ---------------------------------------------------------------------------
__global__ __launch_bounds__(256) void wpack32(const float* __restrict__ w,
                                               char* __restrict__ wpk,
                                               float* __restrict__ stats) {
  if (blockIdx.x == 0 && threadIdx.x < 132) {   // zero ce+ssum+cnt
    *(float4*)(stats + threadIdx.x * 4) = make_float4(0.f, 0.f, 0.f, 0.f);
  }
  int t = blockIdx.x * 256 + threadIdx.x;       // 0..16383
  int c = t >> 9;
  int kstep = (t >> 7) & 3;
  int ehalf = (t >> 6) & 1;
  int lane = t & 63;
  int e = ehalf * 32 + (lane & 31);
  int k = c * 64 + kstep * 16 + ((lane >> 5) << 3);
  const float* p = w + (size_t)e * HDIM + k;
  bf16x8 h8, m8, l8;
  split8(*(const float4*)p, *(const float4*)(p + 4), h8, m8, l8);
  union { bf16x8 v; uint4 u; } H, M, L;
  H.v = h8; M.v = m8; L.v = l8;
  size_t base = (size_t)c * 24576 + (size_t)kstep * 6144 + (size_t)ehalf * 3072
              + (size_t)lane * 16;
  *(uint4*)(wpk + base) = H.u;
  *(uint4*)(wpk + base + 1024) = M.u;
  *(uint4*)(wpk + base + 2048) = L.u;
}

// ---------------------------------------------------------------------------
// Fused gate. 512 blocks x 256 thr (4 waves), 2 blocks/CU (r9 structure).
// 32x32x16 MFMA: block = 32 tok x 64 exp = two 32x32 tiles; wave (wc, kh) =
// expert-tile wc, K-half kh (k-split pair per tile, merged deterministically
// in the epilogue: kh0 writes sc, barrier, kh1 adds).
//   X: f32 staged via gl_lds, per-lane A-frag-swizzled source; split3 at read.
//   W: bf16x3 fragment-linear via gl_lds.
// LDS: W dbuf 2x24KB @0, X dbuf 2x8KB @49152 = 64KB -> 2 blocks/CU.
// vmcnt(0)+barrier per chunk (r9-verbatim).
// A-frag: row = lane&31, k-slot = (lane>>5)*8.  C: col(=e)=lane&31,
// row(=tok) = (reg&3)+8*(reg>>2)+4*(lane>>5)  [m74/m101].
// ---------------------------------------------------------------------------
__global__ __launch_bounds__(256, 2) void gate_fused(const float* __restrict__ x,
                                                     const char* __restrict__ wpk,
                                                     float* __restrict__ out,
                                                     float* __restrict__ ce,
                                                     float* __restrict__ ssum,
                                                     int* __restrict__ cnt) {
  __shared__ __align__(16) char lds[65536];
  __shared__ float hist[NE];
  __shared__ int lastflag;

  const int tid = threadIdx.x;
  const int bid = blockIdx.x;
  const int t0 = bid * BT;
  const int b = bid >> 7;                     // 128 blocks per batch row
  const int lane = tid & 63;
  const int wid = tid >> 6;                   // 0..3
  const int wc = wid & 1;                     // expert tile (32 experts)
  const int kh = wid >> 1;                    // K-half (ksteps kh*2, kh*2+1)

  if (tid < NE) hist[tid] = 0.f;

  // X staging: 2 slots/thread, s = r*256+tid; s = kstep*128 + q*64 + ln.
  // Slot holds x[t0 + (ln&31)][c*64 + kstep*16 + (ln>>5)*8 + q*4 .. +3]
  const char* xsg[2];
  int xdo_[2];
#pragma unroll
  for (int r = 0; r < 2; ++r) {
    int s = r * 256 + tid;
    int ks_ = s >> 7, q = (s >> 6) & 1, ln = s & 63;
    xsg[r] = (const char*)(x + (size_t)(t0 + (ln & 31)) * HDIM
                           + ks_ * 16 + ((ln >> 5) << 3) + q * 4);
    xdo_[r] = (r * 256 + wid * 64) * 16;      // wave-uniform dest offset
  }
  const char* wsrc = wpk + (size_t)lane * 16;

  f32x16 acc = {0.f, 0.f, 0.f, 0.f, 0.f, 0.f, 0.f, 0.f,
                0.f, 0.f, 0.f, 0.f, 0.f, 0.f, 0.f, 0.f};

#define STAGE(cc, sel)                                                        \
  {                                                                           \
    const char* wp_ = wsrc + (size_t)(cc) * 24576;                            \
    char* wd_ = lds + (sel) * 24576;                                          \
    _Pragma("unroll")                                                         \
    for (int i = 0; i < 6; ++i)                                               \
      gl_lds16(wp_ + (i * 4 + wid) * 1024, wd_ + (i * 4 + wid) * 1024);       \
    char* xdst = lds + 49152 + (sel) * 8192;                                  \
    _Pragma("unroll")                                                         \
    for (int r = 0; r < 2; ++r)                                               \
      gl_lds16(xsg[r] + (size_t)(cc) * 256, xdst + xdo_[r]);                  \
  }

  // ---- prologue: stage chunk 0, drain, barrier
  STAGE(0, 0);
  asm volatile("s_waitcnt vmcnt(0)" ::: "memory");
  __builtin_amdgcn_s_barrier();
  asm volatile("" ::: "memory");

#pragma unroll 1
  for (int c = 0; c < NC; ++c) {
    const int sel = c & 1;
    if (c + 1 < NC) STAGE(c + 1, sel ^ 1);    // 1: stage next chunk (async)

    char* wb = lds + sel * 24576;
    char* xb = lds + 49152 + sel * 8192;
#pragma unroll
    for (int kk = 0; kk < 2; ++kk) {          // 2: this wave's two ksteps
      const int ks_ = kh * 2 + kk;
      float4 X0 = *(const float4*)(xb + ks_ * 2048 + lane * 16);
      float4 X1 = *(const float4*)(xb + ks_ * 2048 + 1024 + lane * 16);
      bf16x8 ah, am, al;
      split8(X0, X1, ah, am, al);
      const char* wk = wb + ks_ * 6144 + wc * 3072 + lane * 16;
      bf16x8 bh = *(const bf16x8*)(wk);
      bf16x8 bm = *(const bf16x8*)(wk + 1024);
      bf16x8 bl = *(const bf16x8*)(wk + 2048);
      acc = __builtin_amdgcn_mfma_f32_32x32x16_bf16(ah, bh, acc, 0, 0, 0);
      acc = __builtin_amdgcn_mfma_f32_32x32x16_bf16(ah, bm, acc, 0, 0, 0);
      acc = __builtin_amdgcn_mfma_f32_32x32x16_bf16(am, bh, acc, 0, 0, 0);
      acc = __builtin_amdgcn_mfma_f32_32x32x16_bf16(ah, bl, acc, 0, 0, 0);
      acc = __builtin_amdgcn_mfma_f32_32x32x16_bf16(al, bh, acc, 0, 0, 0);
      acc = __builtin_amdgcn_mfma_f32_32x32x16_bf16(am, bm, acc, 0, 0, 0);
    }
    // 3: drain the staging issued at top of THIS chunk; barrier
    asm volatile("s_waitcnt vmcnt(0)" ::: "memory");
    __builtin_amdgcn_s_barrier();
    asm volatile("" ::: "memory");
  }
#undef STAGE

  // ---- deterministic k-split merge into sc[expert][token] (overlays lds).
  // C layout (32x32): e = wc*32 + (lane&31), tok = (r&3)+8*(r>>2)+4*(lane>>5)
  float (*sc)[BT + 1] = (float(*)[BT + 1])lds;
  __syncthreads();                            // all K-loop LDS reads done
  const int ce_ = wc * 32 + (lane & 31);
  const int tb_ = 4 * (lane >> 5);
  if (kh == 0) {
#pragma unroll
    for (int r = 0; r < 16; ++r)
      sc[ce_][(r & 3) + 8 * (r >> 2) + tb_] = acc[r];
  }
  __syncthreads();
  if (kh == 1) {
#pragma unroll
    for (int r = 0; r < 16; ++r)
      sc[ce_][(r & 3) + 8 * (r >> 2) + tb_] += acc[r];
  }
  __syncthreads();

  // softmax + top-8: 8 lanes per token (t = 0..31), 8 experts per lane
  const int t = tid >> 3;
  const int j = tid & 7;
  float p[8];
#pragma unroll
  for (int i = 0; i < 8; ++i) p[i] = sc[j * 8 + i][t];

  float m = p[0];
#pragma unroll
  for (int i = 1; i < 8; ++i) m = fmaxf(m, p[i]);
  m = fmaxf(m, __shfl_xor(m, 1, 8));
  m = fmaxf(m, __shfl_xor(m, 2, 8));
  m = fmaxf(m, __shfl_xor(m, 4, 8));
  float s = 0.f;
#pragma unroll
  for (int i = 0; i < 8; ++i) { p[i] = __expf(p[i] - m); s += p[i]; }
  s += __shfl_xor(s, 1, 8);
  s += __shfl_xor(s, 2, 8);
  s += __shfl_xor(s, 4, 8);
  float inv = 1.f / s;
#pragma unroll
  for (int i = 0; i < 8; ++i) { p[i] *= inv; sc[j * 8 + i][t] = p[i]; }

  // top-8: strict-> scan (lowest idx on tie), 8-lane (val,idx) reduce
  unsigned used = 0;
  float wsum = 0.f;
  float wv[KTOP];
  int wi_[KTOP];
#pragma unroll
  for (int sel = 0; sel < KTOP; ++sel) {
    float bv = -1.f;
    int bi = 0;
#pragma unroll
    for (int i = 0; i < 8; ++i) {
      bool ok = !((used >> i) & 1u);
      if (ok && p[i] > bv) { bv = p[i]; bi = i; }
    }
    int ge = j * 8 + bi;
#pragma unroll
    for (int mk = 1; mk < 8; mk <<= 1) {
      float ov = __shfl_xor(bv, mk, 8);
      int og = __shfl_xor(ge, mk, 8);
      if (ov > bv || (ov == bv && og < ge)) { bv = ov; ge = og; }
    }
    if ((ge >> 3) == j) used |= 1u << (ge & 7);
    wv[sel] = bv;
    wi_[sel] = ge;
    wsum += bv;
  }
  if (j == 0) {
    float winv = 1.f / (wsum + 1e-20f);
#pragma unroll
    for (int sel = 0; sel < KTOP; ++sel) {
      out[(size_t)(t0 + t) * KTOP + sel] = (float)wi_[sel];
      out[(size_t)TOK * KTOP + (size_t)(t0 + t) * KTOP + sel] = wv[sel] * winv;
      atomicAdd(&hist[wi_[sel]], 1.f);
    }
  }
  __syncthreads();

  if (tid < NE) {
    float ssl = 0.f;
#pragma unroll
    for (int tt = 0; tt < BT; ++tt) ssl += sc[tid][tt];
    atomicAdd(&ssum[b * NE + tid], ssl);
    atomicAdd(&ce[b * NE + tid], hist[tid]);
  }

  // ---- merged finalize: last block computes loads + aux_loss (r11-proven).
  __threadfence();
  __syncthreads();
  if (tid == 0) lastflag = (atomicAdd(cnt, 1) == (int)gridDim.x - 1);
  __syncthreads();
  if (lastflag && tid < 64) {
    const int e = tid;
    float loads = 0.f, aux = 0.f;
#pragma unroll
    for (int b2 = 0; b2 < NB; ++b2) {
      float cv = atomicAdd(&ce[b2 * 64 + e], 0.f);
      float sv = atomicAdd(&ssum[b2 * 64 + e], 0.f);
      loads += cv;
      aux += (cv / 512.0f) * (sv / 4096.0f);  // (S*K/E)=512, S=4096
    }
    out[(size_t)2 * TOK * KTOP + 1 + e] = loads;
#pragma unroll
    for (int off = 32; off > 0; off >>= 1) aux += __shfl_down(aux, off);
    if (e == 0) out[(size_t)2 * TOK * KTOP] = aux * (0.1f / 4.0f);  // ALPHA/B
  }
}

extern "C" void kernel_launch(void* const* d_in, const int* in_sizes, int n_in,
                              void* d_out, int out_size, void* d_ws, size_t ws_size,
                              hipStream_t stream) {
  const float* x = (const float*)d_in[0];
  const float* w = (const float*)d_in[1];
  float* out = (float*)d_out;

  char* wpk = (char*)d_ws;                          // 32 chunks x 24 KB = 768 KB
  float* ce = (float*)(wpk + (size_t)NC * 24576);   // [NB][NE]
  float* ssum = ce + NB * NE;                       // [NB][NE]
  int* cnt = (int*)(ssum + NB * NE);                // completion counter

  wpack32<<<dim3(64), dim3(256), 0, stream>>>(w, wpk, ce);
  gate_fused<<<dim3(TOK / BT), dim3(256), 0, stream>>>(x, wpk, out, ce, ssum, cnt);
}

// Round 13
// 93.662 us; speedup vs baseline: 1.2745x; 1.0106x over previous
//
#include <hip/hip_runtime.h>
#include <hip/hip_bf16.h>
#include <math.h>

#define TOK 16384
#define HDIM 2048
#define NE 64
#define NB 4
#define KTOP 8
#define KC 64
#define NC (HDIM / KC)   // 32 chunks
#define BT 64            // tokens per block

typedef __attribute__((ext_vector_type(8))) __bf16 bf16x8;
typedef __attribute__((ext_vector_type(4))) float f32x4;
typedef unsigned int uint;

__device__ __forceinline__ uint asu(float f) { union { float f; uint u; } c; c.f = f; return c.u; }
__device__ __forceinline__ float asf(uint u) { union { uint u; float f; } c; c.u = u; return c.f; }

// Exact 3-way bf16 split: h+m+l == x bitwise (8 mantissa bits per plane).
__device__ __forceinline__ void split3(float v, uint& h, uint& m, uint& l) {
  uint u = asu(v);
  h = u & 0xffff0000u;
  float d = v - asf(h);
  m = asu(d) & 0xffff0000u;
  float d2 = d - asf(m);
  l = asu(d2);
}

// 8 floats (one fragment k-slot) -> 3 bf16x8 planes, in-register.
__device__ __forceinline__ void split8(float4 a, float4 b,
                                       bf16x8& h8, bf16x8& m8, bf16x8& l8) {
  union { uint4 u; bf16x8 v; } H, M, L;
  uint h0, m0, l0, h1, m1, l1;
  split3(a.x, h0, m0, l0); split3(a.y, h1, m1, l1);
  H.u.x = (h0 >> 16) | (h1 & 0xffff0000u);
  M.u.x = (m0 >> 16) | (m1 & 0xffff0000u);
  L.u.x = (l0 >> 16) | (l1 & 0xffff0000u);
  split3(a.z, h0, m0, l0); split3(a.w, h1, m1, l1);
  H.u.y = (h0 >> 16) | (h1 & 0xffff0000u);
  M.u.y = (m0 >> 16) | (m1 & 0xffff0000u);
  L.u.y = (l0 >> 16) | (l1 & 0xffff0000u);
  split3(b.x, h0, m0, l0); split3(b.y, h1, m1, l1);
  H.u.z = (h0 >> 16) | (h1 & 0xffff0000u);
  M.u.z = (m0 >> 16) | (m1 & 0xffff0000u);
  L.u.z = (l0 >> 16) | (l1 & 0xffff0000u);
  split3(b.z, h0, m0, l0); split3(b.w, h1, m1, l1);
  H.u.w = (h0 >> 16) | (h1 & 0xffff0000u);
  M.u.w = (m0 >> 16) | (m1 & 0xffff0000u);
  L.u.w = (l0 >> 16) | (l1 & 0xffff0000u);
  h8 = H.v; m8 = M.v; l8 = L.v;
}

__device__ __forceinline__ void gl_lds16(const void* g, void* l) {
  __builtin_amdgcn_global_load_lds(
      (const __attribute__((address_space(1))) void*)g,
      (__attribute__((address_space(3))) void*)l, 16, 0, 0);
}

// ---------------------------------------------------------------------------
// wsplit: pack W into 16x16x32 B-fragment order, 3 exact bf16 planes; zero
// stats.  byte = c*24576 + ks*12288 + half*6144 + f2*3072 + plane*1024 + lane*16
// Fragment (c,ks,half,f2,plane,lane): e = half*32+f2*16+(lane&15),
//                                     k = c*64+ks*32+(lane>>4)*8
// ---------------------------------------------------------------------------
__global__ __launch_bounds__(256) void wsplit(const float* __restrict__ w,
                                              char* __restrict__ wpk,
                                              float* __restrict__ stats) {
  if (blockIdx.x == 0 && threadIdx.x < 132) {   // zero ce+ssum+cnt
    *(float4*)(stats + threadIdx.x * 4) = make_float4(0.f, 0.f, 0.f, 0.f);
  }
  int t = blockIdx.x * 256 + threadIdx.x;    // 16384 threads
  int lane = t & 63;
  int f2 = (t >> 6) & 1, half = (t >> 7) & 1, ks = (t >> 8) & 1, c = t >> 9;
  int e = half * 32 + f2 * 16 + (lane & 15);
  int k = c * 64 + ks * 32 + ((lane >> 4) << 3);
  const float* p = w + (size_t)e * HDIM + k;
  bf16x8 h8, m8, l8;
  split8(*(const float4*)p, *(const float4*)(p + 4), h8, m8, l8);
  union { bf16x8 v; uint4 u; } H, M, L;
  H.v = h8; M.v = m8; L.v = l8;
  size_t base = (size_t)c * 24576 + (size_t)ks * 12288 + (size_t)half * 6144
              + (size_t)f2 * 3072 + (size_t)lane * 16;
  *(uint4*)(wpk + base) = H.u;
  *(uint4*)(wpk + base + 1024) = M.u;
  *(uint4*)(wpk + base + 2048) = L.u;
}

// ---------------------------------------------------------------------------
// Fused gate. 256 blocks x 512 thr (8 waves), 1 block/CU -> W is staged ONCE
// per CU per chunk (r9 staged it twice via 2 blocks: the ~20 B/cy/CU gl_lds
// delivery path is the measured wall; 64 -> 40 KB/chunk/CU is the lever).
// Wave = 16 tokens x 32 experts (2 C-frags); tg = wid>>1 (0..3), half = wid&1.
//   X: f32 via gl_lds, per-lane A-frag-swizzled source (m173), dbuf 2x16 KB.
//   W: bf16x3 fragment-linear via gl_lds, dbuf 2x24 KB.
// vmcnt(0)+barrier per chunk (r9-verbatim discipline; X-reg prefetch is
// toxic per r5/r8/r10 -- everything flows through gl_lds).
// LDS: W 2x24K @0, X 2x16K @49152 = 80 KB.
// ---------------------------------------------------------------------------
__global__ __launch_bounds__(512) void gate_fused(const float* __restrict__ x,
                                                  const char* __restrict__ wpk,
                                                  float* __restrict__ out,
                                                  float* __restrict__ ce,
                                                  float* __restrict__ ssum,
                                                  int* __restrict__ cnt) {
  __shared__ __align__(16) char lds[81920];
  __shared__ float hist[NE];
  __shared__ int lastflag;

  const int tid = threadIdx.x;
  const int bid = blockIdx.x;
  const int t0 = bid * BT;
  const int b = bid >> 6;                     // 64 blocks per batch row
  const int lane = tid & 63;
  const int wid = tid >> 6;                   // 0..7
  const int half = wid & 1;                   // expert half
  const int tg = wid >> 1;                    // token group 0..3 (16 tok each)

  if (tid < NE) hist[tid] = 0.f;

  // X staging: 2 slots/thread, s = r*512 + tid; s = tg(2b)|ks(1b)|q(1b)|ln(6b).
  // Slot holds x[t0 + tg*16 + (ln&15)][c*64 + ks*32 + (ln>>4)*8 + q*4 .. +3]
  const char* xsg[2];
  int xdo_[2];
#pragma unroll
  for (int r = 0; r < 2; ++r) {
    int s = r * 512 + tid;
    int stg = s >> 8, sks = (s >> 7) & 1, sq = (s >> 6) & 1, ln = s & 63;
    xsg[r] = (const char*)(x + (size_t)(t0 + stg * 16 + (ln & 15)) * HDIM
                           + sks * 32 + ((ln >> 4) << 3) + sq * 4);
    xdo_[r] = (r * 512 + wid * 64) * 16;      // wave-uniform dest offset
  }
  const char* wsrc = wpk + (size_t)lane * 16;

  f32x4 acc[2] = {{0.f, 0.f, 0.f, 0.f}, {0.f, 0.f, 0.f, 0.f}};

#define STAGE(cc, sel)                                                        \
  {                                                                           \
    const char* wp_ = wsrc + (size_t)(cc) * 24576;                            \
    char* wd_ = lds + (sel) * 24576;                                          \
    _Pragma("unroll")                                                         \
    for (int i = 0; i < 3; ++i)                                               \
      gl_lds16(wp_ + (i * 8 + wid) * 1024, wd_ + (i * 8 + wid) * 1024);       \
    char* xdst = lds + 49152 + (sel) * 16384;                                 \
    _Pragma("unroll")                                                         \
    for (int r = 0; r < 2; ++r)                                               \
      gl_lds16(xsg[r] + (size_t)(cc) * 256, xdst + xdo_[r]);                  \
  }

  // ---- prologue: stage chunk 0, drain, barrier
  STAGE(0, 0);
  asm volatile("s_waitcnt vmcnt(0)" ::: "memory");
  __builtin_amdgcn_s_barrier();
  asm volatile("" ::: "memory");

#pragma unroll 1
  for (int c = 0; c < NC; ++c) {
    const int sel = c & 1;
    if (c + 1 < NC) STAGE(c + 1, sel ^ 1);    // 1: stage next chunk (async)

    char* wb = lds + sel * 24576;
    char* xb = lds + 49152 + sel * 16384 + tg * 4096;
#pragma unroll
    for (int ks = 0; ks < 2; ++ks) {          // 2: X from LDS, split, MFMA
      float4 X0 = *(const float4*)(xb + ks * 2048 + lane * 16);
      float4 X1 = *(const float4*)(xb + ks * 2048 + 1024 + lane * 16);
      bf16x8 ah, am, al;
      split8(X0, X1, ah, am, al);
      const char* wk = wb + ks * 12288 + half * 6144 + lane * 16;
#pragma unroll
      for (int f2 = 0; f2 < 2; ++f2) {
        const char* bb = wk + f2 * 3072;
        bf16x8 bh = *(const bf16x8*)(bb);
        bf16x8 bm = *(const bf16x8*)(bb + 1024);
        bf16x8 bl = *(const bf16x8*)(bb + 2048);
        acc[f2] = __builtin_amdgcn_mfma_f32_16x16x32_bf16(ah, bh, acc[f2], 0, 0, 0);
        acc[f2] = __builtin_amdgcn_mfma_f32_16x16x32_bf16(ah, bm, acc[f2], 0, 0, 0);
        acc[f2] = __builtin_amdgcn_mfma_f32_16x16x32_bf16(am, bh, acc[f2], 0, 0, 0);
        acc[f2] = __builtin_amdgcn_mfma_f32_16x16x32_bf16(ah, bl, acc[f2], 0, 0, 0);
        acc[f2] = __builtin_amdgcn_mfma_f32_16x16x32_bf16(al, bh, acc[f2], 0, 0, 0);
        acc[f2] = __builtin_amdgcn_mfma_f32_16x16x32_bf16(am, bm, acc[f2], 0, 0, 0);
      }
    }
    // 3: drain the staging issued at top of THIS chunk; barrier
    asm volatile("s_waitcnt vmcnt(0)" ::: "memory");
    __builtin_amdgcn_s_barrier();
    asm volatile("" ::: "memory");
  }
#undef STAGE

  // C frags -> sc[expert][token]. C layout: col(=expert)=lane&15,
  // row(=token)=(lane>>4)*4+reg  [m89-verified]
  float (*sc)[BT + 1] = (float(*)[BT + 1])lds;
#pragma unroll
  for (int f2 = 0; f2 < 2; ++f2) {
    int e = half * 32 + f2 * 16 + (lane & 15);
    int tk = tg * 16 + ((lane >> 4) << 2);
    sc[e][tk + 0] = acc[f2][0];
    sc[e][tk + 1] = acc[f2][1];
    sc[e][tk + 2] = acc[f2][2];
    sc[e][tk + 3] = acc[f2][3];
  }
  __syncthreads();

  // softmax + top-8: 8 lanes per token (t = 0..63), 8 experts per lane
  const int t = tid >> 3;
  const int j = tid & 7;
  float p[8];
#pragma unroll
  for (int i = 0; i < 8; ++i) p[i] = sc[j * 8 + i][t];

  float m = p[0];
#pragma unroll
  for (int i = 1; i < 8; ++i) m = fmaxf(m, p[i]);
  m = fmaxf(m, __shfl_xor(m, 1, 8));
  m = fmaxf(m, __shfl_xor(m, 2, 8));
  m = fmaxf(m, __shfl_xor(m, 4, 8));
  float s = 0.f;
#pragma unroll
  for (int i = 0; i < 8; ++i) { p[i] = __expf(p[i] - m); s += p[i]; }
  s += __shfl_xor(s, 1, 8);
  s += __shfl_xor(s, 2, 8);
  s += __shfl_xor(s, 4, 8);
  float inv = 1.f / s;
#pragma unroll
  for (int i = 0; i < 8; ++i) { p[i] *= inv; sc[j * 8 + i][t] = p[i]; }

  // top-8: strict-> scan (lowest idx on tie), 8-lane (val,idx) reduce
  unsigned used = 0;
  float wsum = 0.f;
  float wv[KTOP];
  int wi_[KTOP];
#pragma unroll
  for (int sel = 0; sel < KTOP; ++sel) {
    float bv = -1.f;
    int bi = 0;
#pragma unroll
    for (int i = 0; i < 8; ++i) {
      bool ok = !((used >> i) & 1u);
      if (ok && p[i] > bv) { bv = p[i]; bi = i; }
    }
    int ge = j * 8 + bi;
#pragma unroll
    for (int mk = 1; mk < 8; mk <<= 1) {
      float ov = __shfl_xor(bv, mk, 8);
      int og = __shfl_xor(ge, mk, 8);
      if (ov > bv || (ov == bv && og < ge)) { bv = ov; ge = og; }
    }
    if ((ge >> 3) == j) used |= 1u << (ge & 7);
    wv[sel] = bv;
    wi_[sel] = ge;
    wsum += bv;
  }
  if (j == 0) {
    float winv = 1.f / (wsum + 1e-20f);
#pragma unroll
    for (int sel = 0; sel < KTOP; ++sel) {
      out[(size_t)(t0 + t) * KTOP + sel] = (float)wi_[sel];
      out[(size_t)TOK * KTOP + (size_t)(t0 + t) * KTOP + sel] = wv[sel] * winv;
      atomicAdd(&hist[wi_[sel]], 1.f);
    }
  }
  __syncthreads();

  if (tid < NE) {
    float ssl = 0.f;
#pragma unroll
    for (int tt = 0; tt < BT; ++tt) ssl += sc[tid][tt];
    atomicAdd(&ssum[b * NE + tid], ssl);
    atomicAdd(&ce[b * NE + tid], hist[tid]);
  }

  // ---- merged finalize: last block computes loads + aux_loss.
  __threadfence();
  __syncthreads();
  if (tid == 0) lastflag = (atomicAdd(cnt, 1) == (int)gridDim.x - 1);
  __syncthreads();
  if (lastflag && tid < 64) {
    const int e = tid;
    float loads = 0.f, aux = 0.f;
#pragma unroll
    for (int b2 = 0; b2 < NB; ++b2) {
      float cv = atomicAdd(&ce[b2 * 64 + e], 0.f);
      float sv = atomicAdd(&ssum[b2 * 64 + e], 0.f);
      loads += cv;
      aux += (cv / 512.0f) * (sv / 4096.0f);  // (S*K/E)=512, S=4096
    }
    out[(size_t)2 * TOK * KTOP + 1 + e] = loads;
#pragma unroll
    for (int off = 32; off > 0; off >>= 1) aux += __shfl_down(aux, off);
    if (e == 0) out[(size_t)2 * TOK * KTOP] = aux * (0.1f / 4.0f);  // ALPHA/B
  }
}

extern "C" void kernel_launch(void* const* d_in, const int* in_sizes, int n_in,
                              void* d_out, int out_size, void* d_ws, size_t ws_size,
                              hipStream_t stream) {
  const float* x = (const float*)d_in[0];
  const float* w = (const float*)d_in[1];
  float* out = (float*)d_out;

  char* wpk = (char*)d_ws;                          // 32 chunks x 24 KB = 768 KB
  float* ce = (float*)(wpk + (size_t)NC * 24576);   // [NB][NE]
  float* ssum = ce + NB * NE;                       // [NB][NE]
  int* cnt = (int*)(ssum + NB * NE);                // completion counter

  wsplit<<<dim3(64), dim3(256), 0, stream>>>(w, wpk, ce);
  gate_fused<<<dim3(TOK / BT), dim3(512), 0, stream>>>(x, wpk, out, ce, ssum, cnt);
}